// Round 21
// baseline (303.880 us; speedup 1.0000x reference)
//
#include <hip/hip_runtime.h>
#include <cstdint>
#include <cstddef>

#define N_NODES_C 200000
#define N_EDGES_C 600000
#define NUM_GRAPHS_C 20000

constexpr float NEG_SLOPE = 0.2f;
constexpr float LN_EPS = 1e-5f;

typedef __attribute__((ext_vector_type(8))) short bf16x8;
typedef __attribute__((ext_vector_type(4))) float f32x4;

// bf16 helpers (RNE)
static __device__ __forceinline__ unsigned short f2bf(float f) {
  unsigned u = __float_as_uint(f);
  u = (u + 0x7fffu + ((u >> 16) & 1u)) >> 16;
  return (unsigned short)u;
}
static __device__ __forceinline__ float bf2f(unsigned short s) {
  return __uint_as_float(((unsigned)s) << 16);
}
// unpack packed pair of bf16 from a dword (1 VALU each)
static __device__ __forceinline__ float bfu_lo(unsigned u) {
  return __uint_as_float(u << 16);
}
static __device__ __forceinline__ float bfu_hi(unsigned u) {
  return __uint_as_float(u & 0xffff0000u);
}

// ---------------- CSR build ----------------

__global__ __launch_bounds__(256) void count_deg_kernel(const int* __restrict__ dst,
                                                        int* __restrict__ deg, int E) {
  int e = blockIdx.x * 256 + threadIdx.x;
  if (e < E) atomicAdd(&deg[dst[e]], 1);
}

// exclusive scan over n_total elements; elements with idx < npad are
// transformed deg -> ceil(deg/4)*4 (pad rows to x4; no extra dummy block).
__global__ __launch_bounds__(256) void scan_kernel(const int* __restrict__ in,
                                                   int* __restrict__ out,
                                                   int* __restrict__ bsums,
                                                   int n_total, int npad) {
  __shared__ int ss[256];
  int t = threadIdx.x;
  int base = blockIdx.x * 1024 + t * 4;
  int v[4];
  int s = 0;
#pragma unroll
  for (int j = 0; j < 4; ++j) {
    int idx = base + j;
    int x = (idx < n_total) ? in[idx] : 0;
    if (idx < npad) x = (x + 3) & ~3;
    v[j] = x;
    s += x;
  }
  ss[t] = s;
  __syncthreads();
  for (int off = 1; off < 256; off <<= 1) {
    int x = (t >= off) ? ss[t - off] : 0;
    __syncthreads();
    ss[t] += x;
    __syncthreads();
  }
  int incl = ss[t];
  int excl = incl - s;
  if (bsums != nullptr && t == 255) bsums[blockIdx.x] = incl;
  int run = excl;
#pragma unroll
  for (int j = 0; j < 4; ++j) {
    if (base + j < n_total) out[base + j] = run;
    run += v[j];
  }
}

__global__ __launch_bounds__(256) void scan_addoff_kernel(int* __restrict__ data,
                                                          const int* __restrict__ boff,
                                                          int n_total) {
  int base = blockIdx.x * 1024 + threadIdx.x * 4;
  int add = boff[blockIdx.x];
#pragma unroll
  for (int j = 0; j < 4; ++j) {
    if (base + j < n_total) data[base + j] += add;
  }
}

// fused: scatter edges into CSR slots (i < E) + fill pad slots with dummy
// node N (i >= E covers node index i-E). Writes are disjoint.
__global__ __launch_bounds__(256) void fill_pad_kernel(const int* __restrict__ src,
                                                       const int* __restrict__ dst,
                                                       const int* __restrict__ row_ptr,
                                                       const int* __restrict__ deg,
                                                       int* __restrict__ cursor,
                                                       int* __restrict__ col, int E,
                                                       int n) {
  int i = blockIdx.x * 256 + threadIdx.x;
  if (i < E) {
    int d = dst[i];
    int p = atomicAdd(&cursor[d], 1);
    col[row_ptr[d] + p] = src[i];
  } else {
    int v = i - E;
    if (v < n) {
      int s = row_ptr[v] + deg[v];
      int e = row_ptr[v + 1];
#pragma unroll 1
      for (int j = s; j < e; ++j) col[j] = n;
    }
  }
}

// fused setup: graph_ptr from sorted batch (i <= n) + W1/W2 prep (i < 128*136)
// + dummy-node scores. All independent elementwise work.
__global__ __launch_bounds__(256) void setup_kernel(
    const int* __restrict__ batch, int* __restrict__ gp, int n, int G,
    const float* __restrict__ W1, const float* __restrict__ W2,
    unsigned short* __restrict__ wt1, unsigned short* __restrict__ wt2,
    float* __restrict__ asrc1, float* __restrict__ asrc2) {
  int i = blockIdx.x * 256 + threadIdx.x;
  if (i < n) {
    int prev = (i == 0) ? -1 : batch[i - 1];
    int cur = batch[i];
#pragma unroll 1
    for (int g = prev + 1; g <= cur; ++g) gp[g] = i;
  } else if (i == n) {
    int last = batch[n - 1];
#pragma unroll 1
    for (int g = last + 1; g <= G; ++g) gp[g] = n;
  }
  if (i < 128 * 136) {
    int nn = i / 136, k = i % 136;
    unsigned short z = 0;
    wt1[i] = (k < 128) ? f2bf(W1[(size_t)k * 128 + nn]) : z;
    wt2[i] = (k < 128) ? f2bf(W2[(size_t)k * 128 + nn]) : z;
  }
  if (i < 4) asrc1[(size_t)n * 4 + i] = -1e30f;
  if (i == 4) asrc2[n] = -1e30f;
}

// ---------------- MFMA GEMM + att-score epilogue ----------------
// Round-21: amortize W staging. 3125 tiles = 625 blocks x 5 tiles; each block
// stages the 34.8KB W image ONCE, then loops over 5 consecutive 64-row tiles
// (round-18/20 analysis: per-block W re-stage + barrier was the fixed cost
// that kept gemm at ~60us, 2.5-3.5x above its ~20us HBM floor; 625 blocks
// are fully co-resident at 4 blocks/CU). A fragments are lane-private
// global->VGPR loads (round-20 scheme); W from LDS (round-19 lesson).

template <int H, bool A_BF16>
__global__ __launch_bounds__(256) void gemm_att_mfma(
    const void* __restrict__ Av, const unsigned short* __restrict__ Wtp,
    const float* __restrict__ att_src, const float* __restrict__ att_dst,
    unsigned short* __restrict__ Cbf, float* __restrict__ asrc,
    float* __restrict__ adst) {
  __shared__ __align__(16) unsigned short Wlds[128 * 136];
  int tid = threadIdx.x;
  int lane = tid & 63;
  int wave = tid >> 6;
  int l15 = lane & 15;
  int lg = lane >> 4;
  int wr = wave * 16;

  // stage W image once: linear copy, 2176 chunks of 8 shorts (L2-resident)
#pragma unroll
  for (int i = 0; i < 9; ++i) {
    int ch = tid + i * 256;
    if (ch < 2176) *(bf16x8*)&Wlds[ch * 8] = *(const bf16x8*)&Wtp[(size_t)ch * 8];
  }
  __syncthreads();

  // att vectors: tile-invariant, load once
  float vsv[8], vdv[8];
#pragma unroll
  for (int nt = 0; nt < 8; ++nt) {
    vsv[nt] = att_src[nt * 16 + l15];
    vdv[nt] = att_dst[nt * 16 + l15];
  }

#pragma unroll 1
  for (int t = 0; t < 5; ++t) {
    int row0 = (blockIdx.x * 5 + t) * 64;
    int arow = row0 + wr + l15;

    // A fragments: global -> regs (lane-private rows)
    bf16x8 afrag[4];
    if constexpr (A_BF16) {
      const unsigned short* A = (const unsigned short*)Av;
      afrag[0] = *(const bf16x8*)(A + (size_t)arow * 128 + 0 * 32 + lg * 8);
      afrag[1] = *(const bf16x8*)(A + (size_t)arow * 128 + 1 * 32 + lg * 8);
      afrag[2] = *(const bf16x8*)(A + (size_t)arow * 128 + 2 * 32 + lg * 8);
      afrag[3] = *(const bf16x8*)(A + (size_t)arow * 128 + 3 * 32 + lg * 8);
    } else {
      const float* A = (const float*)Av;
      float4 fa0 = *(const float4*)(A + (size_t)arow * 128 + 0 * 32 + lg * 8);
      float4 fa1 = *(const float4*)(A + (size_t)arow * 128 + 0 * 32 + lg * 8 + 4);
      float4 fa2 = *(const float4*)(A + (size_t)arow * 128 + 1 * 32 + lg * 8);
      float4 fa3 = *(const float4*)(A + (size_t)arow * 128 + 1 * 32 + lg * 8 + 4);
      float4 fa4 = *(const float4*)(A + (size_t)arow * 128 + 2 * 32 + lg * 8);
      float4 fa5 = *(const float4*)(A + (size_t)arow * 128 + 2 * 32 + lg * 8 + 4);
      float4 fa6 = *(const float4*)(A + (size_t)arow * 128 + 3 * 32 + lg * 8);
      float4 fa7 = *(const float4*)(A + (size_t)arow * 128 + 3 * 32 + lg * 8 + 4);
      unsigned short t0[8] = {f2bf(fa0.x), f2bf(fa0.y), f2bf(fa0.z), f2bf(fa0.w),
                              f2bf(fa1.x), f2bf(fa1.y), f2bf(fa1.z), f2bf(fa1.w)};
      afrag[0] = *(bf16x8*)t0;
      unsigned short t1[8] = {f2bf(fa2.x), f2bf(fa2.y), f2bf(fa2.z), f2bf(fa2.w),
                              f2bf(fa3.x), f2bf(fa3.y), f2bf(fa3.z), f2bf(fa3.w)};
      afrag[1] = *(bf16x8*)t1;
      unsigned short t2[8] = {f2bf(fa4.x), f2bf(fa4.y), f2bf(fa4.z), f2bf(fa4.w),
                              f2bf(fa5.x), f2bf(fa5.y), f2bf(fa5.z), f2bf(fa5.w)};
      afrag[2] = *(bf16x8*)t2;
      unsigned short t3[8] = {f2bf(fa6.x), f2bf(fa6.y), f2bf(fa6.z), f2bf(fa6.w),
                              f2bf(fa7.x), f2bf(fa7.y), f2bf(fa7.z), f2bf(fa7.w)};
      afrag[3] = *(bf16x8*)t3;
    }

    f32x4 acc[8];
#pragma unroll
    for (int nt = 0; nt < 8; ++nt) acc[nt] = (f32x4){0.f, 0.f, 0.f, 0.f};

#pragma unroll
    for (int ks = 0; ks < 4; ++ks) {
#pragma unroll
      for (int nt = 0; nt < 8; ++nt) {
        bf16x8 bfr = *(const bf16x8*)&Wlds[(nt * 16 + l15) * 136 + ks * 32 + lg * 8];
        acc[nt] =
            __builtin_amdgcn_mfma_f32_16x16x32_bf16(afrag[ks], bfr, acc[nt], 0, 0, 0);
      }
    }

#pragma unroll
    for (int r = 0; r < 4; ++r) {
      int row = row0 + wr + lg * 4 + r;
#pragma unroll
      for (int nt = 0; nt < 8; ++nt) {
        Cbf[(size_t)row * 128 + nt * 16 + l15] = f2bf(acc[nt][r]);
      }
      if constexpr (H == 4) {
        float ps[4], pd[4];
#pragma unroll
        for (int hd = 0; hd < 4; ++hd) {
          ps[hd] = acc[2 * hd][r] * vsv[2 * hd] + acc[2 * hd + 1][r] * vsv[2 * hd + 1];
          pd[hd] = acc[2 * hd][r] * vdv[2 * hd] + acc[2 * hd + 1][r] * vdv[2 * hd + 1];
#pragma unroll
          for (int off = 1; off < 16; off <<= 1) {
            ps[hd] += __shfl_xor(ps[hd], off, 64);
            pd[hd] += __shfl_xor(pd[hd], off, 64);
          }
        }
        if (l15 < 4) {
          float pss =
              (l15 == 0) ? ps[0] : (l15 == 1) ? ps[1] : (l15 == 2) ? ps[2] : ps[3];
          float pds =
              (l15 == 0) ? pd[0] : (l15 == 1) ? pd[1] : (l15 == 2) ? pd[2] : pd[3];
          asrc[(size_t)row * 4 + l15] = pss;
          adst[(size_t)row * 4 + l15] = pds;
        }
      } else {
        float ps = 0.f, pd = 0.f;
#pragma unroll
        for (int nt = 0; nt < 8; ++nt) {
          ps = fmaf(acc[nt][r], vsv[nt], ps);
          pd = fmaf(acc[nt][r], vdv[nt], pd);
        }
#pragma unroll
        for (int off = 1; off < 16; off <<= 1) {
          ps += __shfl_xor(ps, off, 64);
          pd += __shfl_xor(pd, off, 64);
        }
        if (l15 == 0) {
          asrc[row] = ps;
          adst[row] = pd;
        }
      }
    }
  }
}

// ---------------- Pass B: half-wave per node, one pair per wave (round 16) --

template <int H, bool RELU, bool LNOUT>
__global__ __launch_bounds__(256) void gat_agg6_kernel(
    const unsigned short* __restrict__ h, const float* __restrict__ asrc,
    const float* __restrict__ adst, const int* __restrict__ row_ptr,
    const int* __restrict__ col, const float* __restrict__ bias,
    const float* __restrict__ gamma, const float* __restrict__ beta,
    unsigned short* __restrict__ outbf, int n) {
  int wid = (blockIdx.x * 256 + threadIdx.x) >> 6;
  int lane = threadIdx.x & 63;
  int half = lane >> 5;
  int cl = lane & 31;
  int node = wid * 2 + half;  // n even -> wave-uniform validity
  if (node >= n) return;

  int e0 = row_ptr[node];
  int len = row_ptr[node + 1] - e0;  // padded to x4
  int c0 = cl * 4;
  const int hd = (H == 1) ? 0 : (cl >> 3);  // 32 channels per head

  float ad = (H == 4) ? adst[(size_t)node * 4 + hd] : adst[node];
  float as_ = (H == 4) ? asrc[(size_t)node * 4 + hd] : asrc[node];
  float x = as_ + ad;
  x = (x > 0.f) ? x : NEG_SLOPE * x;
  float selfe = __expf(x);
  float den = selfe;

  float a0, a1, a2, a3;
  {
    uint2 hs = *(const uint2*)(h + (size_t)node * 128 + c0);
    a0 = bfu_lo(hs.x) * selfe;
    a1 = bfu_hi(hs.x) * selfe;
    a2 = bfu_lo(hs.y) * selfe;
    a3 = bfu_hi(hs.y) * selfe;
  }

#pragma unroll 1
  for (int t = 0; t < len; t += 4) {
    int4 s4 = *(const int4*)(col + e0 + t);  // 16B aligned
    float sc0, sc1, sc2, sc3;
    if constexpr (H == 4) {
      sc0 = asrc[(size_t)s4.x * 4 + hd];
      sc1 = asrc[(size_t)s4.y * 4 + hd];
      sc2 = asrc[(size_t)s4.z * 4 + hd];
      sc3 = asrc[(size_t)s4.w * 4 + hd];
    } else {
      sc0 = asrc[s4.x];
      sc1 = asrc[s4.y];
      sc2 = asrc[s4.z];
      sc3 = asrc[s4.w];
    }
    uint2 h0 = *(const uint2*)(h + (size_t)s4.x * 128 + c0);
    uint2 h1 = *(const uint2*)(h + (size_t)s4.y * 128 + c0);
    uint2 h2 = *(const uint2*)(h + (size_t)s4.z * 128 + c0);
    uint2 h3 = *(const uint2*)(h + (size_t)s4.w * 128 + c0);

    float y0 = sc0 + ad; y0 = (y0 > 0.f) ? y0 : NEG_SLOPE * y0;
    float e0f = __expf(y0);
    float y1 = sc1 + ad; y1 = (y1 > 0.f) ? y1 : NEG_SLOPE * y1;
    float e1f = __expf(y1);
    float y2 = sc2 + ad; y2 = (y2 > 0.f) ? y2 : NEG_SLOPE * y2;
    float e2f = __expf(y2);
    float y3 = sc3 + ad; y3 = (y3 > 0.f) ? y3 : NEG_SLOPE * y3;
    float e3f = __expf(y3);
    den += e0f + e1f + e2f + e3f;

    a0 = fmaf(bfu_lo(h0.x), e0f, a0);
    a1 = fmaf(bfu_hi(h0.x), e0f, a1);
    a2 = fmaf(bfu_lo(h0.y), e0f, a2);
    a3 = fmaf(bfu_hi(h0.y), e0f, a3);
    a0 = fmaf(bfu_lo(h1.x), e1f, a0);
    a1 = fmaf(bfu_hi(h1.x), e1f, a1);
    a2 = fmaf(bfu_lo(h1.y), e1f, a2);
    a3 = fmaf(bfu_hi(h1.y), e1f, a3);
    a0 = fmaf(bfu_lo(h2.x), e2f, a0);
    a1 = fmaf(bfu_hi(h2.x), e2f, a1);
    a2 = fmaf(bfu_lo(h2.y), e2f, a2);
    a3 = fmaf(bfu_hi(h2.y), e2f, a3);
    a0 = fmaf(bfu_lo(h3.x), e3f, a0);
    a1 = fmaf(bfu_hi(h3.x), e3f, a1);
    a2 = fmaf(bfu_lo(h3.y), e3f, a2);
    a3 = fmaf(bfu_hi(h3.y), e3f, a3);
  }

  float inv = 1.f / den;
  float4 b4 = *(const float4*)(bias + c0);
  float o0 = fmaf(a0, inv, b4.x);
  float o1 = fmaf(a1, inv, b4.y);
  float o2 = fmaf(a2, inv, b4.z);
  float o3 = fmaf(a3, inv, b4.w);
  if (RELU) {
    o0 = fmaxf(o0, 0.f);
    o1 = fmaxf(o1, 0.f);
    o2 = fmaxf(o2, 0.f);
    o3 = fmaxf(o3, 0.f);
  }

  if (!LNOUT) {
    uint2 pv;
    pv.x = (unsigned)f2bf(o0) | ((unsigned)f2bf(o1) << 16);
    pv.y = (unsigned)f2bf(o2) | ((unsigned)f2bf(o3) << 16);
    *(uint2*)(outbf + (size_t)node * 128 + c0) = pv;
  } else {
    float ssum = o0 + o1 + o2 + o3;
#pragma unroll
    for (int off = 1; off < 32; off <<= 1) ssum += __shfl_xor(ssum, off, 64);
    float mu = ssum * (1.f / 128.f);
    float d0 = o0 - mu, d1 = o1 - mu, d2 = o2 - mu, d3 = o3 - mu;
    float vs2 = d0 * d0 + d1 * d1 + d2 * d2 + d3 * d3;
#pragma unroll
    for (int off = 1; off < 32; off <<= 1) vs2 += __shfl_xor(vs2, off, 64);
    float ivn = rsqrtf(vs2 * (1.f / 128.f) + LN_EPS);
    float4 g4 = *(const float4*)(gamma + c0);
    float4 be4 = *(const float4*)(beta + c0);
    float q0 = fmaf(d0 * ivn, g4.x, be4.x);
    float q1 = fmaf(d1 * ivn, g4.y, be4.y);
    float q2 = fmaf(d2 * ivn, g4.z, be4.z);
    float q3 = fmaf(d3 * ivn, g4.w, be4.w);
    uint2 pv;
    pv.x = (unsigned)f2bf(q0) | ((unsigned)f2bf(q1) << 16);
    pv.y = (unsigned)f2bf(q2) | ((unsigned)f2bf(q3) << 16);
    *(uint2*)(outbf + (size_t)node * 128 + c0) = pv;
  }
}

// ---------------- mean pool: one wave per graph, contiguous rows -------------

__global__ __launch_bounds__(256) void pool_kernel(const unsigned short* __restrict__ hln,
                                                   const int* __restrict__ gp,
                                                   float* __restrict__ out, int G) {
  int g = (blockIdx.x * 256 + threadIdx.x) >> 6;
  int lane = threadIdx.x & 63;
  if (g >= G) return;
  int s = gp[g], e = gp[g + 1];
  float ax = 0.f, ay = 0.f;
#pragma unroll 1
  for (int i = s; i < e; ++i) {
    unsigned v = *(const unsigned*)(hln + (size_t)i * 128 + lane * 2);
    ax += bfu_lo(v);
    ay += bfu_hi(v);
  }
  int c = e - s;
  float sc = 1.f / (float)((c > 0) ? c : 1);
  *(float2*)(out + (size_t)g * 128 + lane * 2) = make_float2(ax * sc, ay * sc);
}

// ---------------- launch ----------------

extern "C" void kernel_launch(void* const* d_in, const int* in_sizes, int n_in,
                              void* d_out, int out_size, void* d_ws, size_t ws_size,
                              hipStream_t stream) {
  const float* x = (const float*)d_in[0];
  const int* ei = (const int*)d_in[1];
  const int* batch = (const int*)d_in[2];
  const float* W1 = (const float*)d_in[3];
  const float* att_src1 = (const float*)d_in[4];
  const float* att_dst1 = (const float*)d_in[5];
  const float* b1 = (const float*)d_in[6];
  const float* W2 = (const float*)d_in[7];
  const float* att_src2 = (const float*)d_in[8];
  const float* att_dst2 = (const float*)d_in[9];
  const float* b2 = (const float*)d_in[10];
  const float* gamma = (const float*)d_in[11];
  const float* beta = (const float*)d_in[12];
  float* out = (float*)d_out;

  const int N = N_NODES_C, E = N_EDGES_C, G = NUM_GRAPHS_C;
  const int COLSZ = E + 3 * N + 16;  // padded CSR upper bound (pad <= 3/row)
  const int* src = ei;
  const int* dst = ei + E;

  float* p = (float*)d_ws;
  float* asrc1 = p; p += (size_t)(N + 1) * 4;  // +dummy row (asrc[N]=-1e30)
  float* adst1 = p; p += (size_t)N * 4;
  float* asrc2 = p; p += N + 1;
  float* adst2 = p; p += N;
  int* ip = (int*)p;
  int* deg = ip;       ip += N + 1;  // deg[N]=0; adjacent to cursor (one memset)
  int* cursor = ip;    ip += N;
  int* col = ip;       ip += COLSZ;
  int* bsums = ip;     ip += 256;
  int* bsums2 = ip;    ip += 256;
  int* row_ptr = ip;   ip += N + 2;
  int* graph_ptr = ip; ip += G + 2;
  unsigned short* h1bf = (unsigned short*)ip;          // [(N+1)*128] bf16 (+dummy row)
  unsigned short* hbbf = h1bf + (size_t)(N + 1) * 128;
  unsigned short* h2bf = hbbf + (size_t)(N + 1) * 128;
  unsigned short* wt1 = h2bf + (size_t)(N + 1) * 128;  // [128*136] bf16 W^T padded
  unsigned short* wt2 = wt1 + 128 * 136;
  (void)ws_size; (void)in_sizes; (void)n_in; (void)out_size;

  // deg (N+1) and cursor (N) are adjacent: single memset
  hipMemsetAsync(deg, 0, sizeof(int) * (size_t)(2 * N + 1), stream);

  // CSR (rows padded to x4) + fused setup (graph_ptr, W prep, dummy scores)
  count_deg_kernel<<<(E + 255) / 256, 256, 0, stream>>>(dst, deg, E);
  int nblk = (N + 1 + 1023) / 1024;
  scan_kernel<<<nblk, 256, 0, stream>>>(deg, row_ptr, bsums, N + 1, N);
  scan_kernel<<<1, 256, 0, stream>>>(bsums, bsums2, nullptr, nblk, 0);
  scan_addoff_kernel<<<nblk, 256, 0, stream>>>(row_ptr, bsums2, N + 1);
  fill_pad_kernel<<<(E + N + 255) / 256, 256, 0, stream>>>(src, dst, row_ptr, deg,
                                                           cursor, col, E, N);
  setup_kernel<<<(N + 1 + 255) / 256, 256, 0, stream>>>(
      batch, graph_ptr, N, G, W1, W2, wt1, wt2, asrc1, asrc2);

  int pblocks = N / 8;     // 2 nodes/wave, 4 waves/block; 200000/8 exact
  int gblocks = N / 320;   // 625 blocks x 5 tiles x 64 rows = 200000 exactly

  // Layer 1: GAT(128 -> 4x32), ReLU
  gemm_att_mfma<4, false><<<gblocks, 256, 0, stream>>>(
      x, wt1, att_src1, att_dst1, h1bf, asrc1, adst1);
  gat_agg6_kernel<4, true, false><<<pblocks, 256, 0, stream>>>(
      h1bf, asrc1, adst1, row_ptr, col, b1, nullptr, nullptr, hbbf, N);

  // Layer 2: GAT(128 -> 1x128) + fused LayerNorm -> bf16 rows
  gemm_att_mfma<1, true><<<gblocks, 256, 0, stream>>>(
      hbbf, wt2, att_src2, att_dst2, h2bf, asrc2, adst2);
  gat_agg6_kernel<1, false, true><<<pblocks, 256, 0, stream>>>(
      h2bf, asrc2, adst2, row_ptr, col, b2, gamma, beta, h1bf, N);

  // mean pool per graph: contiguous segmented reduction -> d_out
  pool_kernel<<<(int)(((size_t)G * 64 + 255) / 256), 256, 0, stream>>>(
      h1bf, graph_ptr, out, G);
}

// Round 22
// 284.857 us; speedup vs baseline: 1.0668x; 1.0668x over previous
//
#include <hip/hip_runtime.h>
#include <cstdint>
#include <cstddef>

#define N_NODES_C 200000
#define N_EDGES_C 600000
#define NUM_GRAPHS_C 20000

constexpr float NEG_SLOPE = 0.2f;
constexpr float LN_EPS = 1e-5f;

typedef __attribute__((ext_vector_type(8))) short bf16x8;
typedef __attribute__((ext_vector_type(4))) float f32x4;

// bf16 helpers (RNE)
static __device__ __forceinline__ unsigned short f2bf(float f) {
  unsigned u = __float_as_uint(f);
  u = (u + 0x7fffu + ((u >> 16) & 1u)) >> 16;
  return (unsigned short)u;
}
static __device__ __forceinline__ float bf2f(unsigned short s) {
  return __uint_as_float(((unsigned)s) << 16);
}
// unpack packed pair of bf16 from a dword (1 VALU each)
static __device__ __forceinline__ float bfu_lo(unsigned u) {
  return __uint_as_float(u << 16);
}
static __device__ __forceinline__ float bfu_hi(unsigned u) {
  return __uint_as_float(u & 0xffff0000u);
}

// ---------------- CSR build ----------------

__global__ __launch_bounds__(256) void count_deg_kernel(const int* __restrict__ dst,
                                                        int* __restrict__ deg, int E) {
  int e = blockIdx.x * 256 + threadIdx.x;
  if (e < E) atomicAdd(&deg[dst[e]], 1);
}

// exclusive scan over n_total elements; elements with idx < npad are
// transformed deg -> ceil(deg/4)*4 (pad rows to x4; no extra dummy block).
__global__ __launch_bounds__(256) void scan_kernel(const int* __restrict__ in,
                                                   int* __restrict__ out,
                                                   int* __restrict__ bsums,
                                                   int n_total, int npad) {
  __shared__ int ss[256];
  int t = threadIdx.x;
  int base = blockIdx.x * 1024 + t * 4;
  int v[4];
  int s = 0;
#pragma unroll
  for (int j = 0; j < 4; ++j) {
    int idx = base + j;
    int x = (idx < n_total) ? in[idx] : 0;
    if (idx < npad) x = (x + 3) & ~3;
    v[j] = x;
    s += x;
  }
  ss[t] = s;
  __syncthreads();
  for (int off = 1; off < 256; off <<= 1) {
    int x = (t >= off) ? ss[t - off] : 0;
    __syncthreads();
    ss[t] += x;
    __syncthreads();
  }
  int incl = ss[t];
  int excl = incl - s;
  if (bsums != nullptr && t == 255) bsums[blockIdx.x] = incl;
  int run = excl;
#pragma unroll
  for (int j = 0; j < 4; ++j) {
    if (base + j < n_total) out[base + j] = run;
    run += v[j];
  }
}

__global__ __launch_bounds__(256) void scan_addoff_kernel(int* __restrict__ data,
                                                          const int* __restrict__ boff,
                                                          int n_total) {
  int base = blockIdx.x * 1024 + threadIdx.x * 4;
  int add = boff[blockIdx.x];
#pragma unroll
  for (int j = 0; j < 4; ++j) {
    if (base + j < n_total) data[base + j] += add;
  }
}

// fused: scatter edges into CSR slots (i < E) + fill pad slots with dummy
// node N (i >= E covers node index i-E). Writes are disjoint.
__global__ __launch_bounds__(256) void fill_pad_kernel(const int* __restrict__ src,
                                                       const int* __restrict__ dst,
                                                       const int* __restrict__ row_ptr,
                                                       const int* __restrict__ deg,
                                                       int* __restrict__ cursor,
                                                       int* __restrict__ col, int E,
                                                       int n) {
  int i = blockIdx.x * 256 + threadIdx.x;
  if (i < E) {
    int d = dst[i];
    int p = atomicAdd(&cursor[d], 1);
    col[row_ptr[d] + p] = src[i];
  } else {
    int v = i - E;
    if (v < n) {
      int s = row_ptr[v] + deg[v];
      int e = row_ptr[v + 1];
#pragma unroll 1
      for (int j = s; j < e; ++j) col[j] = n;
    }
  }
}

// fused setup: graph_ptr from sorted batch (i <= n) + W1/W2 prep (i < 128*136)
// + dummy-node scores. All independent elementwise work.
__global__ __launch_bounds__(256) void setup_kernel(
    const int* __restrict__ batch, int* __restrict__ gp, int n, int G,
    const float* __restrict__ W1, const float* __restrict__ W2,
    unsigned short* __restrict__ wt1, unsigned short* __restrict__ wt2,
    float* __restrict__ asrc1, float* __restrict__ asrc2) {
  int i = blockIdx.x * 256 + threadIdx.x;
  if (i < n) {
    int prev = (i == 0) ? -1 : batch[i - 1];
    int cur = batch[i];
#pragma unroll 1
    for (int g = prev + 1; g <= cur; ++g) gp[g] = i;
  } else if (i == n) {
    int last = batch[n - 1];
#pragma unroll 1
    for (int g = last + 1; g <= G; ++g) gp[g] = n;
  }
  if (i < 128 * 136) {
    int nn = i / 136, k = i % 136;
    unsigned short z = 0;
    wt1[i] = (k < 128) ? f2bf(W1[(size_t)k * 128 + nn]) : z;
    wt2[i] = (k < 128) ? f2bf(W2[(size_t)k * 128 + nn]) : z;
  }
  if (i < 4) asrc1[(size_t)n * 4 + i] = -1e30f;
  if (i == 4) asrc2[n] = -1e30f;
}

// ---------------- MFMA GEMM + att-score epilogue (round-18 verified) --------
// Alds + Wlds staging, 3125 blocks, 3 blocks/CU. Rounds 19-21 tested W-from-
// global (latency-poison), A-from-global (neutral), and 5x W-amortization
// (grid collapse to 2.4 waves/SIMD): none beat this configuration — its
// ~60us is a structural local optimum for the 64-row tile decomposition.

template <int H, bool A_BF16>
__global__ __launch_bounds__(256) void gemm_att_mfma(
    const void* __restrict__ Av, const unsigned short* __restrict__ Wtp,
    const float* __restrict__ att_src, const float* __restrict__ att_dst,
    unsigned short* __restrict__ Cbf, float* __restrict__ asrc,
    float* __restrict__ adst) {
  __shared__ __align__(16) unsigned short Alds[64 * 136];
  __shared__ __align__(16) unsigned short Wlds[128 * 136];
  int tid = threadIdx.x;
  int lane = tid & 63;
  int wave = tid >> 6;
  int row0 = blockIdx.x * 64;

#pragma unroll
  for (int i = 0; i < 9; ++i) {
    int ch = tid + i * 256;
    if (ch < 2176) *(bf16x8*)&Wlds[ch * 8] = *(const bf16x8*)&Wtp[(size_t)ch * 8];
  }
#pragma unroll
  for (int i = 0; i < 4; ++i) {
    int ch = tid + i * 256;
    int r = ch >> 4, c = ch & 15;
    if constexpr (A_BF16) {
      bf16x8 v = *(const bf16x8*)((const unsigned short*)Av +
                                  (size_t)(row0 + r) * 128 + c * 8);
      *(bf16x8*)&Alds[r * 136 + c * 8] = v;
    } else {
      const float* A = (const float*)Av;
      float4 v0 = *(const float4*)(A + (size_t)(row0 + r) * 128 + c * 8);
      float4 v1 = *(const float4*)(A + (size_t)(row0 + r) * 128 + c * 8 + 4);
      unsigned short tmp[8] = {f2bf(v0.x), f2bf(v0.y), f2bf(v0.z), f2bf(v0.w),
                               f2bf(v1.x), f2bf(v1.y), f2bf(v1.z), f2bf(v1.w)};
      *(bf16x8*)&Alds[r * 136 + c * 8] = *(bf16x8*)tmp;
    }
  }
  __syncthreads();

  int l15 = lane & 15;
  int lg = lane >> 4;
  int wr = wave * 16;

  f32x4 acc[8];
#pragma unroll
  for (int nt = 0; nt < 8; ++nt) acc[nt] = (f32x4){0.f, 0.f, 0.f, 0.f};

#pragma unroll
  for (int ks = 0; ks < 4; ++ks) {
    bf16x8 af = *(const bf16x8*)&Alds[(wr + l15) * 136 + ks * 32 + lg * 8];
#pragma unroll
    for (int nt = 0; nt < 8; ++nt) {
      bf16x8 bfr = *(const bf16x8*)&Wlds[(nt * 16 + l15) * 136 + ks * 32 + lg * 8];
      acc[nt] = __builtin_amdgcn_mfma_f32_16x16x32_bf16(af, bfr, acc[nt], 0, 0, 0);
    }
  }

  float vsv[8], vdv[8];
#pragma unroll
  for (int nt = 0; nt < 8; ++nt) {
    vsv[nt] = att_src[nt * 16 + l15];
    vdv[nt] = att_dst[nt * 16 + l15];
  }

#pragma unroll
  for (int r = 0; r < 4; ++r) {
    int row = row0 + wr + lg * 4 + r;
#pragma unroll
    for (int nt = 0; nt < 8; ++nt) {
      Cbf[(size_t)row * 128 + nt * 16 + l15] = f2bf(acc[nt][r]);
    }
    if constexpr (H == 4) {
      float ps[4], pd[4];
#pragma unroll
      for (int hd = 0; hd < 4; ++hd) {
        ps[hd] = acc[2 * hd][r] * vsv[2 * hd] + acc[2 * hd + 1][r] * vsv[2 * hd + 1];
        pd[hd] = acc[2 * hd][r] * vdv[2 * hd] + acc[2 * hd + 1][r] * vdv[2 * hd + 1];
#pragma unroll
        for (int off = 1; off < 16; off <<= 1) {
          ps[hd] += __shfl_xor(ps[hd], off, 64);
          pd[hd] += __shfl_xor(pd[hd], off, 64);
        }
      }
      if (l15 < 4) {
        float pss = (l15 == 0) ? ps[0] : (l15 == 1) ? ps[1] : (l15 == 2) ? ps[2] : ps[3];
        float pds = (l15 == 0) ? pd[0] : (l15 == 1) ? pd[1] : (l15 == 2) ? pd[2] : pd[3];
        asrc[(size_t)row * 4 + l15] = pss;
        adst[(size_t)row * 4 + l15] = pds;
      }
    } else {
      float ps = 0.f, pd = 0.f;
#pragma unroll
      for (int nt = 0; nt < 8; ++nt) {
        ps = fmaf(acc[nt][r], vsv[nt], ps);
        pd = fmaf(acc[nt][r], vdv[nt], pd);
      }
#pragma unroll
      for (int off = 1; off < 16; off <<= 1) {
        ps += __shfl_xor(ps, off, 64);
        pd += __shfl_xor(pd, off, 64);
      }
      if (l15 == 0) {
        asrc[row] = ps;
        adst[row] = pd;
      }
    }
  }
}

// ---------------- Pass B: half-wave per node, one pair per wave (round 16) --

template <int H, bool RELU, bool LNOUT>
__global__ __launch_bounds__(256) void gat_agg6_kernel(
    const unsigned short* __restrict__ h, const float* __restrict__ asrc,
    const float* __restrict__ adst, const int* __restrict__ row_ptr,
    const int* __restrict__ col, const float* __restrict__ bias,
    const float* __restrict__ gamma, const float* __restrict__ beta,
    unsigned short* __restrict__ outbf, int n) {
  int wid = (blockIdx.x * 256 + threadIdx.x) >> 6;
  int lane = threadIdx.x & 63;
  int half = lane >> 5;
  int cl = lane & 31;
  int node = wid * 2 + half;  // n even -> wave-uniform validity
  if (node >= n) return;

  int e0 = row_ptr[node];
  int len = row_ptr[node + 1] - e0;  // padded to x4
  int c0 = cl * 4;
  const int hd = (H == 1) ? 0 : (cl >> 3);  // 32 channels per head

  float ad = (H == 4) ? adst[(size_t)node * 4 + hd] : adst[node];
  float as_ = (H == 4) ? asrc[(size_t)node * 4 + hd] : asrc[node];
  float x = as_ + ad;
  x = (x > 0.f) ? x : NEG_SLOPE * x;
  float selfe = __expf(x);
  float den = selfe;

  float a0, a1, a2, a3;
  {
    uint2 hs = *(const uint2*)(h + (size_t)node * 128 + c0);
    a0 = bfu_lo(hs.x) * selfe;
    a1 = bfu_hi(hs.x) * selfe;
    a2 = bfu_lo(hs.y) * selfe;
    a3 = bfu_hi(hs.y) * selfe;
  }

#pragma unroll 1
  for (int t = 0; t < len; t += 4) {
    int4 s4 = *(const int4*)(col + e0 + t);  // 16B aligned
    float sc0, sc1, sc2, sc3;
    if constexpr (H == 4) {
      sc0 = asrc[(size_t)s4.x * 4 + hd];
      sc1 = asrc[(size_t)s4.y * 4 + hd];
      sc2 = asrc[(size_t)s4.z * 4 + hd];
      sc3 = asrc[(size_t)s4.w * 4 + hd];
    } else {
      sc0 = asrc[s4.x];
      sc1 = asrc[s4.y];
      sc2 = asrc[s4.z];
      sc3 = asrc[s4.w];
    }
    uint2 h0 = *(const uint2*)(h + (size_t)s4.x * 128 + c0);
    uint2 h1 = *(const uint2*)(h + (size_t)s4.y * 128 + c0);
    uint2 h2 = *(const uint2*)(h + (size_t)s4.z * 128 + c0);
    uint2 h3 = *(const uint2*)(h + (size_t)s4.w * 128 + c0);

    float y0 = sc0 + ad; y0 = (y0 > 0.f) ? y0 : NEG_SLOPE * y0;
    float e0f = __expf(y0);
    float y1 = sc1 + ad; y1 = (y1 > 0.f) ? y1 : NEG_SLOPE * y1;
    float e1f = __expf(y1);
    float y2 = sc2 + ad; y2 = (y2 > 0.f) ? y2 : NEG_SLOPE * y2;
    float e2f = __expf(y2);
    float y3 = sc3 + ad; y3 = (y3 > 0.f) ? y3 : NEG_SLOPE * y3;
    float e3f = __expf(y3);
    den += e0f + e1f + e2f + e3f;

    a0 = fmaf(bfu_lo(h0.x), e0f, a0);
    a1 = fmaf(bfu_hi(h0.x), e0f, a1);
    a2 = fmaf(bfu_lo(h0.y), e0f, a2);
    a3 = fmaf(bfu_hi(h0.y), e0f, a3);
    a0 = fmaf(bfu_lo(h1.x), e1f, a0);
    a1 = fmaf(bfu_hi(h1.x), e1f, a1);
    a2 = fmaf(bfu_lo(h1.y), e1f, a2);
    a3 = fmaf(bfu_hi(h1.y), e1f, a3);
    a0 = fmaf(bfu_lo(h2.x), e2f, a0);
    a1 = fmaf(bfu_hi(h2.x), e2f, a1);
    a2 = fmaf(bfu_lo(h2.y), e2f, a2);
    a3 = fmaf(bfu_hi(h2.y), e2f, a3);
    a0 = fmaf(bfu_lo(h3.x), e3f, a0);
    a1 = fmaf(bfu_hi(h3.x), e3f, a1);
    a2 = fmaf(bfu_lo(h3.y), e3f, a2);
    a3 = fmaf(bfu_hi(h3.y), e3f, a3);
  }

  float inv = 1.f / den;
  float4 b4 = *(const float4*)(bias + c0);
  float o0 = fmaf(a0, inv, b4.x);
  float o1 = fmaf(a1, inv, b4.y);
  float o2 = fmaf(a2, inv, b4.z);
  float o3 = fmaf(a3, inv, b4.w);
  if (RELU) {
    o0 = fmaxf(o0, 0.f);
    o1 = fmaxf(o1, 0.f);
    o2 = fmaxf(o2, 0.f);
    o3 = fmaxf(o3, 0.f);
  }

  if (!LNOUT) {
    uint2 pv;
    pv.x = (unsigned)f2bf(o0) | ((unsigned)f2bf(o1) << 16);
    pv.y = (unsigned)f2bf(o2) | ((unsigned)f2bf(o3) << 16);
    *(uint2*)(outbf + (size_t)node * 128 + c0) = pv;
  } else {
    float ssum = o0 + o1 + o2 + o3;
#pragma unroll
    for (int off = 1; off < 32; off <<= 1) ssum += __shfl_xor(ssum, off, 64);
    float mu = ssum * (1.f / 128.f);
    float d0 = o0 - mu, d1 = o1 - mu, d2 = o2 - mu, d3 = o3 - mu;
    float vs2 = d0 * d0 + d1 * d1 + d2 * d2 + d3 * d3;
#pragma unroll
    for (int off = 1; off < 32; off <<= 1) vs2 += __shfl_xor(vs2, off, 64);
    float ivn = rsqrtf(vs2 * (1.f / 128.f) + LN_EPS);
    float4 g4 = *(const float4*)(gamma + c0);
    float4 be4 = *(const float4*)(beta + c0);
    float q0 = fmaf(d0 * ivn, g4.x, be4.x);
    float q1 = fmaf(d1 * ivn, g4.y, be4.y);
    float q2 = fmaf(d2 * ivn, g4.z, be4.z);
    float q3 = fmaf(d3 * ivn, g4.w, be4.w);
    uint2 pv;
    pv.x = (unsigned)f2bf(q0) | ((unsigned)f2bf(q1) << 16);
    pv.y = (unsigned)f2bf(q2) | ((unsigned)f2bf(q3) << 16);
    *(uint2*)(outbf + (size_t)node * 128 + c0) = pv;
  }
}

// ---------------- mean pool: one wave per graph, contiguous rows -------------

__global__ __launch_bounds__(256) void pool_kernel(const unsigned short* __restrict__ hln,
                                                   const int* __restrict__ gp,
                                                   float* __restrict__ out, int G) {
  int g = (blockIdx.x * 256 + threadIdx.x) >> 6;
  int lane = threadIdx.x & 63;
  if (g >= G) return;
  int s = gp[g], e = gp[g + 1];
  float ax = 0.f, ay = 0.f;
#pragma unroll 1
  for (int i = s; i < e; ++i) {
    unsigned v = *(const unsigned*)(hln + (size_t)i * 128 + lane * 2);
    ax += bfu_lo(v);
    ay += bfu_hi(v);
  }
  int c = e - s;
  float sc = 1.f / (float)((c > 0) ? c : 1);
  *(float2*)(out + (size_t)g * 128 + lane * 2) = make_float2(ax * sc, ay * sc);
}

// ---------------- launch ----------------

extern "C" void kernel_launch(void* const* d_in, const int* in_sizes, int n_in,
                              void* d_out, int out_size, void* d_ws, size_t ws_size,
                              hipStream_t stream) {
  const float* x = (const float*)d_in[0];
  const int* ei = (const int*)d_in[1];
  const int* batch = (const int*)d_in[2];
  const float* W1 = (const float*)d_in[3];
  const float* att_src1 = (const float*)d_in[4];
  const float* att_dst1 = (const float*)d_in[5];
  const float* b1 = (const float*)d_in[6];
  const float* W2 = (const float*)d_in[7];
  const float* att_src2 = (const float*)d_in[8];
  const float* att_dst2 = (const float*)d_in[9];
  const float* b2 = (const float*)d_in[10];
  const float* gamma = (const float*)d_in[11];
  const float* beta = (const float*)d_in[12];
  float* out = (float*)d_out;

  const int N = N_NODES_C, E = N_EDGES_C, G = NUM_GRAPHS_C;
  const int COLSZ = E + 3 * N + 16;  // padded CSR upper bound (pad <= 3/row)
  const int* src = ei;
  const int* dst = ei + E;

  float* p = (float*)d_ws;
  float* asrc1 = p; p += (size_t)(N + 1) * 4;  // +dummy row (asrc[N]=-1e30)
  float* adst1 = p; p += (size_t)N * 4;
  float* asrc2 = p; p += N + 1;
  float* adst2 = p; p += N;
  int* ip = (int*)p;
  int* deg = ip;       ip += N + 1;  // deg[N]=0; adjacent to cursor (one memset)
  int* cursor = ip;    ip += N;
  int* col = ip;       ip += COLSZ;
  int* bsums = ip;     ip += 256;
  int* bsums2 = ip;    ip += 256;
  int* row_ptr = ip;   ip += N + 2;
  int* graph_ptr = ip; ip += G + 2;
  unsigned short* h1bf = (unsigned short*)ip;          // [(N+1)*128] bf16 (+dummy row)
  unsigned short* hbbf = h1bf + (size_t)(N + 1) * 128;
  unsigned short* h2bf = hbbf + (size_t)(N + 1) * 128;
  unsigned short* wt1 = h2bf + (size_t)(N + 1) * 128;  // [128*136] bf16 W^T padded
  unsigned short* wt2 = wt1 + 128 * 136;
  (void)ws_size; (void)in_sizes; (void)n_in; (void)out_size;

  // deg (N+1) and cursor (N) are adjacent: single memset
  hipMemsetAsync(deg, 0, sizeof(int) * (size_t)(2 * N + 1), stream);

  // CSR (rows padded to x4) + fused setup (graph_ptr, W prep, dummy scores)
  count_deg_kernel<<<(E + 255) / 256, 256, 0, stream>>>(dst, deg, E);
  int nblk = (N + 1 + 1023) / 1024;
  scan_kernel<<<nblk, 256, 0, stream>>>(deg, row_ptr, bsums, N + 1, N);
  scan_kernel<<<1, 256, 0, stream>>>(bsums, bsums2, nullptr, nblk, 0);
  scan_addoff_kernel<<<nblk, 256, 0, stream>>>(row_ptr, bsums2, N + 1);
  fill_pad_kernel<<<(E + N + 255) / 256, 256, 0, stream>>>(src, dst, row_ptr, deg,
                                                           cursor, col, E, N);
  setup_kernel<<<(N + 1 + 255) / 256, 256, 0, stream>>>(
      batch, graph_ptr, N, G, W1, W2, wt1, wt2, asrc1, asrc2);

  int pblocks = N / 8;   // 2 nodes/wave, 4 waves/block; 200000/8 exact
  int gblocks = N / 64;  // 200000 = 64*3125 exactly

  // Layer 1: GAT(128 -> 4x32), ReLU
  gemm_att_mfma<4, false><<<gblocks, 256, 0, stream>>>(
      x, wt1, att_src1, att_dst1, h1bf, asrc1, adst1);
  gat_agg6_kernel<4, true, false><<<pblocks, 256, 0, stream>>>(
      h1bf, asrc1, adst1, row_ptr, col, b1, nullptr, nullptr, hbbf, N);

  // Layer 2: GAT(128 -> 1x128) + fused LayerNorm -> bf16 rows
  gemm_att_mfma<1, true><<<gblocks, 256, 0, stream>>>(
      hbbf, wt2, att_src2, att_dst2, h2bf, asrc2, adst2);
  gat_agg6_kernel<1, false, true><<<pblocks, 256, 0, stream>>>(
      h2bf, asrc2, adst2, row_ptr, col, b2, gamma, beta, h1bf, N);

  // mean pool per graph: contiguous segmented reduction -> d_out
  pool_kernel<<<(int)(((size_t)G * 64 + 255) / 256), 256, 0, stream>>>(
      h1bf, graph_ptr, out, G);
}